// Round 14
// baseline (43.285 us; speedup 1.0000x reference)
//
#include <hip/hip_runtime.h>

#define IN_SZ 108
#define NPIX (IN_SZ * IN_SZ)
#define MAXR 58                    // crop span <= 56 source rows (+r1 +slack)

typedef float f32x2 __attribute__((ext_vector_type(2)));

__device__ __forceinline__ float maskv(float x, float off, float end) {
    // sigmoid(10*(x-off)) - sigmoid(10*(x-end))
    float a = 1.0f / (1.0f + __expf(-10.0f * (x - off)));
    float b = 1.0f / (1.0f + __expf(-10.0f * (x - end)));
    return a - b;
}

__global__ __launch_bounds__(512) void attn_crop_kernel(
    const float* __restrict__ images,
    const float* __restrict__ locs,
    float* __restrict__ out)
{
    __shared__ __align__(16) float s_img[MAXR * IN_SZ];  // 25056 B staged crop rows
    __shared__ float4 s_row[IN_SZ];   // wr0, wr1, (r0-rbase)*108, (r1-rbase)*108

    const int blk = blockIdx.x;       // img*3 + ch
    const int img = blk / 3;
    const int tid = threadIdx.x;
    const int w   = tid >> 6;         // wave id (0..7)
    const int l   = tid & 63;         // lane

    // ---- per-image box ----
    const float l0 = locs[3 * img + 0];
    const float l1 = locs[3 * img + 1];
    const float l2 = locs[3 * img + 2];
    const float tx = 54.0f + truncf(l0 * 27.0f + 0.5f);
    const float ty = 54.0f + truncf(l1 * 27.0f + 0.5f);
    const float tl = 21.0f + truncf(l2 * 7.0f + 0.5f);
    const float w_off = fmaxf(tx - tl, 0.0f);
    const float h_off = fmaxf(ty - tl, 0.0f);
    const float w_end = fminf(tx + tl, 108.0f);
    const float h_end = fminf(ty + tl, 108.0f);

    const int rbase = min(max((int)w_off, 0), IN_SZ - 1);   // w_off is exact integer
    const int nrows = min(MAXR, IN_SZ - rbase);

    // ---- row table (threads 0..107): offsets rebased to staged region ----
    if (tid < IN_SZ) {
        float fj  = (float)tid;
        float sr  = w_off + (fj * (w_end - w_off - 1.0f)) / 107.0f;  // reference order
        float flr = fminf(fmaxf(floorf(sr), 0.0f), 107.0f);
        int   r0  = min(max((int)flr, rbase), 107);
        int   r1  = min(r0 + 1, 107);
        float fr  = sr - flr;
        float4 p;
        p.x = (1.0f - fr) * maskv((float)r0, w_off, w_end);
        p.y = fr * maskv((float)r1, w_off, w_end);
        p.z = __int_as_float((r0 - rbase) * IN_SZ);
        p.w = __int_as_float((r1 - rbase) * IN_SZ);
        s_row[tid] = p;
    }

    // ---- per-lane column params (cols 2l, 2l+1), loop-invariant ----
    const float cspan = h_end - h_off - 1.0f;
    const int kA = min(2 * l, 107), kB = min(2 * l + 1, 107);
    float scA  = h_off + ((float)kA * cspan) / 107.0f;
    float flA  = fminf(fmaxf(floorf(scA), 0.0f), 107.0f);
    int   c0A  = (int)flA;
    float fcA  = scA - flA;
    float wc0A = (1.0f - fcA) * maskv((float)c0A, h_off, h_end);
    float wc1A = fcA * maskv((float)min(c0A + 1, 107), h_off, h_end);
    float scB  = h_off + ((float)kB * cspan) / 107.0f;
    float flB  = fminf(fmaxf(floorf(scB), 0.0f), 107.0f);
    int   c0B  = (int)flB;
    float fcB  = scB - flB;
    float wc0B = (1.0f - fcB) * maskv((float)c0B, h_off, h_end);
    float wc1B = fcB * maskv((float)min(c0B + 1, 107), h_off, h_end);

    // ---- 4-col window [e, e+3]; zero-weight clamp taps proven exact ----
    const int e  = min(c0A & ~1, 104);
    const int p_ = c0A - e;
    const int q_ = c0B - e;
    const int t2 = min(p_ + 1, 3);
    const int t3 = min(q_ + 1, 3);
    float Wx0 = (p_ == 0 ? wc0A : 0.0f) + (t2 == 0 ? wc1A : 0.0f);
    float Wx1 = (p_ == 1 ? wc0A : 0.0f) + (t2 == 1 ? wc1A : 0.0f);
    float Wx2 = (p_ == 2 ? wc0A : 0.0f) + (t2 == 2 ? wc1A : 0.0f);
    float Wx3 = (p_ == 3 ? wc0A : 0.0f) + (t2 == 3 ? wc1A : 0.0f);
    float Wy0 = (q_ == 0 ? wc0B : 0.0f) + (t3 == 0 ? wc1B : 0.0f);
    float Wy1 = (q_ == 1 ? wc0B : 0.0f) + (t3 == 1 ? wc1B : 0.0f);
    float Wy2 = (q_ == 2 ? wc0B : 0.0f) + (t3 == 2 ? wc1B : 0.0f);
    float Wy3 = (q_ == 3 ? wc0B : 0.0f) + (t3 == 3 ? wc1B : 0.0f);

    // ---- stage crop rows into LDS: coalesced 16B per lane, ~25 wave-loads ----
    {
        const float* __restrict__ gsrc = images + (size_t)blk * NPIX + rbase * IN_SZ;
        const int nfl = nrows * IN_SZ;              // multiple of 4 (108 = 27*4)
        for (int i4 = tid * 4; i4 < nfl; i4 += 512 * 4) {
            *(float4*)(s_img + i4) = *(const float4*)(gsrc + i4);
        }
    }
    __syncthreads();

    float* __restrict__ dstl = out + (size_t)blk * NPIX + 2 * l;
    const float* __restrict__ se = s_img + e;       // lane window base (8B aligned)

    // ---- rows j = w + 8t, t = 0..13 (j<108); R13-proven 2-slot pipeline ----
    float4 pA = s_row[w];
    float4 pB = s_row[w + 8];
    f32x2 Aa0 = *(const f32x2*)(se + __float_as_int(pA.z));
    f32x2 Aa1 = *(const f32x2*)(se + __float_as_int(pA.z) + 2);
    f32x2 Ba0 = *(const f32x2*)(se + __float_as_int(pA.w));
    f32x2 Ba1 = *(const f32x2*)(se + __float_as_int(pA.w) + 2);
    f32x2 Ab0 = *(const f32x2*)(se + __float_as_int(pB.z));
    f32x2 Ab1 = *(const f32x2*)(se + __float_as_int(pB.z) + 2);
    f32x2 Bb0 = *(const f32x2*)(se + __float_as_int(pB.w));
    f32x2 Bb1 = *(const f32x2*)(se + __float_as_int(pB.w) + 2);

    for (int k = 0; k < 7; ++k) {
        // prefetch slots t = 2k+2, 2k+3 (row index clamped; stores guarded)
        float4 pA2 = pA, pB2 = pB;
        f32x2 Aa0n = Aa0, Aa1n = Aa1, Ba0n = Ba0, Ba1n = Ba1;
        f32x2 Ab0n = Ab0, Ab1n = Ab1, Bb0n = Bb0, Bb1n = Bb1;
        if (k < 6) {
            int ja = min(w + 16 * k + 16, 107);
            int jb = min(w + 16 * k + 24, 107);
            pA2 = s_row[ja];
            pB2 = s_row[jb];
            Aa0n = *(const f32x2*)(se + __float_as_int(pA2.z));
            Aa1n = *(const f32x2*)(se + __float_as_int(pA2.z) + 2);
            Ba0n = *(const f32x2*)(se + __float_as_int(pA2.w));
            Ba1n = *(const f32x2*)(se + __float_as_int(pA2.w) + 2);
            Ab0n = *(const f32x2*)(se + __float_as_int(pB2.z));
            Ab1n = *(const f32x2*)(se + __float_as_int(pB2.z) + 2);
            Bb0n = *(const f32x2*)(se + __float_as_int(pB2.w));
            Bb1n = *(const f32x2*)(se + __float_as_int(pB2.w) + 2);
        }
        // row a: j = w + 16k (max 103, always valid)
        {
            f32x2 M0 = Aa0 * pA.x + Ba0 * pA.y;     // v_pk_fma_f32
            f32x2 M1 = Aa1 * pA.x + Ba1 * pA.y;
            f32x2 o;
            o.x = M0.x * Wx0 + M0.y * Wx1 + M1.x * Wx2 + M1.y * Wx3;
            o.y = M0.x * Wy0 + M0.y * Wy1 + M1.x * Wy2 + M1.y * Wy3;
            if (l < 54) *(f32x2*)(dstl + (w + 16 * k) * IN_SZ) = o;
        }
        // row b: j = w + 16k + 8 (invalid for waves 4..7 at k=6)
        {
            const int jrow = w + 16 * k + 8;
            f32x2 M0 = Ab0 * pB.x + Bb0 * pB.y;
            f32x2 M1 = Ab1 * pB.x + Bb1 * pB.y;
            f32x2 o;
            o.x = M0.x * Wx0 + M0.y * Wx1 + M1.x * Wx2 + M1.y * Wx3;
            o.y = M0.x * Wy0 + M0.y * Wy1 + M1.x * Wy2 + M1.y * Wy3;
            if (l < 54 && jrow < IN_SZ) *(f32x2*)(dstl + jrow * IN_SZ) = o;
        }
        pA = pA2; pB = pB2;
        Aa0 = Aa0n; Aa1 = Aa1n; Ba0 = Ba0n; Ba1 = Ba1n;
        Ab0 = Ab0n; Ab1 = Ab1n; Bb0 = Bb0n; Bb1 = Bb1n;
    }
}

extern "C" void kernel_launch(void* const* d_in, const int* in_sizes, int n_in,
                              void* d_out, int out_size, void* d_ws, size_t ws_size,
                              hipStream_t stream) {
    const float* images = (const float*)d_in[0];
    const float* locs   = (const float*)d_in[1];
    float* out = (float*)d_out;
    const int nimg = in_sizes[1] / 3;   // locs is [nimg, 3]
    attn_crop_kernel<<<dim3(nimg * 3), dim3(512), 0, stream>>>(images, locs, out);
}

// Round 15
// 38.953 us; speedup vs baseline: 1.1112x; 1.1112x over previous
//
#include <hip/hip_runtime.h>

#define IN_SZ 108
#define NPIX (IN_SZ * IN_SZ)

typedef float f32x2 __attribute__((ext_vector_type(2)));
typedef float f32x4 __attribute__((ext_vector_type(4)));
typedef f32x4 f32x4u __attribute__((aligned(8)));   // 8B-aligned 16B load

__device__ __forceinline__ f32x4 ld4u(const float* p) { return *(const f32x4u*)p; }

__device__ __forceinline__ float maskv(float x, float off, float end) {
    // sigmoid(10*(x-off)) - sigmoid(10*(x-end))
    float a = 1.0f / (1.0f + __expf(-10.0f * (x - off)));
    float b = 1.0f / (1.0f + __expf(-10.0f * (x - end)));
    return a - b;
}

// weight vector over 4 window slots: tap0 -> slot s0 (weight w0), tap1 -> s1 (w1)
__device__ __forceinline__ f32x4 wvec(int s0, float w0, int s1, float w1) {
    f32x4 v;
    v.x = (s0 == 0 ? w0 : 0.0f) + (s1 == 0 ? w1 : 0.0f);
    v.y = (s0 == 1 ? w0 : 0.0f) + (s1 == 1 ? w1 : 0.0f);
    v.z = (s0 == 2 ? w0 : 0.0f) + (s1 == 2 ? w1 : 0.0f);
    v.w = (s0 == 3 ? w0 : 0.0f) + (s1 == 3 ? w1 : 0.0f);
    return v;
}

__device__ __forceinline__ float dot4(f32x4 a, f32x4 b) {
    return fmaf(a.x, b.x, fmaf(a.y, b.y, fmaf(a.z, b.z, a.w * b.w)));
}

__global__ __launch_bounds__(256) void attn_crop_kernel(
    const float* __restrict__ images,
    const float* __restrict__ locs,
    float* __restrict__ out)
{
    __shared__ float4 s_row[IN_SZ];   // wr0, wr1, r0*108 (bits), r1*108 (bits)

    const int blk = blockIdx.x;       // img*3 + ch
    const int img = blk / 3;
    const int tid = threadIdx.x;
    const int w   = tid >> 6;         // wave id (0..3)
    const int l   = tid & 63;         // lane

    // ---- per-image box ----
    const float l0 = locs[3 * img + 0];
    const float l1 = locs[3 * img + 1];
    const float l2 = locs[3 * img + 2];
    const float tx = 54.0f + truncf(l0 * 27.0f + 0.5f);
    const float ty = 54.0f + truncf(l1 * 27.0f + 0.5f);
    const float tl = 21.0f + truncf(l2 * 7.0f + 0.5f);
    const float w_off = fmaxf(tx - tl, 0.0f);
    const float h_off = fmaxf(ty - tl, 0.0f);
    const float w_end = fminf(tx + tl, 108.0f);
    const float h_end = fminf(ty + tl, 108.0f);

    // ---- row table: built once (one expf pass, threads 0..107) ----
    if (tid < IN_SZ) {
        float fj  = (float)tid;
        float sr  = w_off + (fj * (w_end - w_off - 1.0f)) / 107.0f;  // reference order
        float flr = fminf(fmaxf(floorf(sr), 0.0f), 107.0f);
        int   r0  = (int)flr;
        int   r1  = min(r0 + 1, 107);
        float fr  = sr - flr;
        float4 p;
        p.x = (1.0f - fr) * maskv((float)r0, w_off, w_end);
        p.y = fr * maskv((float)r1, w_off, w_end);
        p.z = __int_as_float(r0 * IN_SZ);
        p.w = __int_as_float(r1 * IN_SZ);
        s_row[tid] = p;
    }

    // ---- lane role: pair block of 216 floats = rows (2p, 2p+1) ----
    // lanes 0..26 -> row 2p cols 4l..4l+3; lanes 27..53 -> row 2p+1 cols 4l-108..
    const int rowsel = (l < 27) ? 0 : 1;
    const int b = min((l < 27) ? 4 * l : 4 * l - 108, 104);   // first of 4 cols

    // ---- per-lane col params for cols b..b+3 (computed once) ----
    const float cspan = h_end - h_off - 1.0f;
    int   c0i[4];
    float w0c[4], w1c[4];
#pragma unroll
    for (int i = 0; i < 4; ++i) {
        int k = b + i;                                        // <= 107
        float sc = h_off + ((float)k * cspan) / 107.0f;       // reference order
        float fl = fminf(fmaxf(floorf(sc), 0.0f), 107.0f);
        int c0 = (int)fl;
        float fc = sc - fl;
        c0i[i] = c0;
        w0c[i] = (1.0f - fc) * maskv((float)c0, h_off, h_end);
        w1c[i] = fc * maskv((float)min(c0 + 1, 107), h_off, h_end);
    }
    // two 4-col windows: [e0,e0+3] serves cols b,b+1; [e1,e1+3] serves b+2,b+3.
    // Slot clamps are exact: any clamped tap provably carries weight 0
    // (c0==107 -> fc==0 since box coords are integer-valued).
    const int e0 = min(c0i[0] & ~1, 104);
    const int e1 = min(c0i[2] & ~1, 104);
    const f32x4 V0 = wvec(min(c0i[0] - e0, 3), w0c[0], min(c0i[0] + 1 - e0, 3), w1c[0]);
    const f32x4 V1 = wvec(min(c0i[1] - e0, 3), w0c[1], min(c0i[1] + 1 - e0, 3), w1c[1]);
    const f32x4 V2 = wvec(min(c0i[2] - e1, 3), w0c[2], min(c0i[2] + 1 - e1, 3), w1c[2]);
    const f32x4 V3 = wvec(min(c0i[3] - e1, 3), w0c[3], min(c0i[3] + 1 - e1, 3), w1c[3]);

    __syncthreads();

    const float* __restrict__ gbase = images + (size_t)blk * NPIX;
    float*       __restrict__ obase = out    + (size_t)blk * NPIX;
    const int npw = (w < 2) ? 14 : 13;       // pairs p = w + 4t, p < 54

    // ---- prologue: pair p0 = w (per-lane param read + 4 window loads) ----
    float4 prm = s_row[2 * w + rowsel];      // one ds_read_b128, 2-way broadcast
    f32x4 W0 = ld4u(gbase + __float_as_int(prm.z) + e0);
    f32x4 X0 = ld4u(gbase + __float_as_int(prm.z) + e1);
    f32x4 W1 = ld4u(gbase + __float_as_int(prm.w) + e0);
    f32x4 X1 = ld4u(gbase + __float_as_int(prm.w) + e1);

    for (int t = 0; t < 14; ++t) {
        // prefetch next pair (distance-1-iter; index clamped, store guarded)
        float4 prmN = prm;
        f32x4 W0n = W0, X0n = X0, W1n = W1, X1n = X1;
        if (t < 13) {
            int pn = min(w + 4 * (t + 1), 53);
            prmN = s_row[2 * pn + rowsel];
            W0n = ld4u(gbase + __float_as_int(prmN.z) + e0);
            X0n = ld4u(gbase + __float_as_int(prmN.z) + e1);
            W1n = ld4u(gbase + __float_as_int(prmN.w) + e0);
            X1n = ld4u(gbase + __float_as_int(prmN.w) + e1);
        }
        // fold rows (wr0, wr1 uniform per lane's row), then 4 col dots
        f32x4 M0 = W0 * prm.x + W1 * prm.y;   // v_pk_fma_f32 x2
        f32x4 M1 = X0 * prm.x + X1 * prm.y;
        f32x4 o;
        o.x = dot4(M0, V0);
        o.y = dot4(M0, V1);
        o.z = dot4(M1, V2);
        o.w = dot4(M1, V3);
        const int p = w + 4 * t;
        if (l < 54 && t < npw)
            *(f32x4*)(obase + 216 * p + 4 * l) = o;   // one 864B wave store/pair
        prm = prmN; W0 = W0n; X0 = X0n; W1 = W1n; X1 = X1n;
    }
}

extern "C" void kernel_launch(void* const* d_in, const int* in_sizes, int n_in,
                              void* d_out, int out_size, void* d_ws, size_t ws_size,
                              hipStream_t stream) {
    const float* images = (const float*)d_in[0];
    const float* locs   = (const float*)d_in[1];
    float* out = (float*)d_out;
    const int nimg = in_sizes[1] / 3;   // locs is [nimg, 3]
    attn_crop_kernel<<<dim3(nimg * 3), dim3(256), 0, stream>>>(images, locs, out);
}